// Round 4
// baseline (655.440 us; speedup 1.0000x reference)
//
#include <hip/hip_runtime.h>
#include <hip/hip_bf16.h>

// out = [relu(A@relu(A@F)) | A@(A@nf)], N=8192, D=E=64.
// Two skinny GEMMs (M=8192, N=128, K=8192), relu on cols<64 after each.
// Round 7 == Round 6 resubmit (bench infra failed twice; kernel never ran).
// Fragment-direct, NO-LDS, NO-barrier GEMM: rounds 4/5 (dbuf prefetch;
// TLP+gl2lds) were both neutral => the shared barrier-coupled LDS skeleton is
// the limiter, not the feed path. With N=128 there is no cross-wave B reuse
// in a block and A reuse is only 4x (L1 covers it), so LDS buys nothing.
// Each wave owns a 16-row C strip, loads A-frags (16-32B/lane, coalesced)
// and B-frags (L2-resident 2MB Bt) directly from global, MFMAs, zero
// barriers. Waves free-run; loads pipeline across iters; latency hidden by
// TLP+ILP. split = low 3 bits of blockIdx => all blocks on an XCD share one
// 256KB Bt k-slice (XCD-local L2 reuse).
// Layer1 f32 path writes its cvt'd bf16 A back to Abf (128MB ws, L3-fits);
// layer2 reads Abf (half the bytes, no cvt). Dtype self-detection retained.

typedef unsigned short ushort_t;
typedef __attribute__((ext_vector_type(8))) short short8;   // 8 bf16 (4 VGPRs)
typedef __attribute__((ext_vector_type(4))) float f32x4;    // MFMA 16x16 acc
typedef __attribute__((ext_vector_type(4))) unsigned short us4;

#define NN 8192
#define NO 128
#define NSPLIT 8
#define KSPAN (NN / NSPLIT)      // 1024
#define KSTEPS (KSPAN / 32)      // 32 MFMA K-steps per block

__global__ void detect_dtype(const ushort_t* __restrict__ A, int* __restrict__ flag) {
  __shared__ int smax, szero;
  const int t = threadIdx.x;
  if (t == 0) { smax = 0; szero = 0; }
  __syncthreads();
  int lmax = 0, lzero = 0;
  #pragma unroll
  for (int j = 0; j < 8; ++j) {
    int idx = t * 8 + j;                 // ushorts [0,2048)
    int u = (int)A[idx];
    if ((idx & 1) == 0) {                // little-endian: even = f32 low mantissa
      lmax = max(lmax, u);
      lzero += (u == 0) ? 1 : 0;
    }
  }
  atomicMax(&smax, lmax);
  atomicAdd(&szero, lzero);
  __syncthreads();
  if (t == 0) *flag = (smax > 0x3A00 || szero > 800) ? 1 : 0;
}

__global__ void zero_ws(float* __restrict__ p) {
  size_t i = ((size_t)blockIdx.x * 256 + threadIdx.x) * 4;
  *(float4*)(p + i) = make_float4(0.f, 0.f, 0.f, 0.f);
}

__device__ __forceinline__ short bf16bits(float x) {
  __hip_bfloat16 h = __float2bfloat16(x);
  return *reinterpret_cast<short*>(&h);
}

__device__ __forceinline__ short8 cvt8(float4 a, float4 b) {
  short8 r;
  r[0] = bf16bits(a.x); r[1] = bf16bits(a.y); r[2] = bf16bits(a.z); r[3] = bf16bits(a.w);
  r[4] = bf16bits(b.x); r[5] = bf16bits(b.y); r[6] = bf16bits(b.z); r[7] = bf16bits(b.w);
  return r;
}

// Bt[n][k] = concat(F,nf)^T as bf16, from either storage dtype.
__global__ void pack_bt(const ushort_t* __restrict__ F, const ushort_t* __restrict__ NF,
                        ushort_t* __restrict__ Bt, const int* __restrict__ flag) {
  int idx = blockIdx.x * 256 + threadIdx.x;   // 131072 threads
  int n = idx >> 10;                           // [0,128)
  int k0 = (idx & 1023) << 3;                  // 8 consecutive k
  ushort_t* dst = Bt + ((size_t)n << 13) + k0;
  if (*flag) {
    const float* src = (n < 64) ? ((const float*)F + n) : ((const float*)NF + (n - 64));
    #pragma unroll
    for (int j = 0; j < 8; ++j) dst[j] = (ushort_t)bf16bits(src[(size_t)(k0 + j) << 6]);
  } else {
    const ushort_t* src = (n < 64) ? (F + n) : (NF + (n - 64));
    #pragma unroll
    for (int j = 0; j < 8; ++j) dst[j] = src[(size_t)(k0 + j) << 6];
  }
}

// Fragment-direct GEMM, no LDS, no barriers.
// mfma_f32_16x16x32_bf16 (verified layouts):
//   A-frag lane l -> A[m=l&15][k=(l>>4)*8+j]  => lane reads 16B at row l&15.
//   B-frag lane l -> B[k=(l>>4)*8+j][n=l&15]  => lane reads Bt[n=l&15 row][16B].
//   C/D: col=l&15, row=(l>>4)*4+reg.
// Each wave: 16-row strip, full 128 output cols (8 n-tiles), KSPAN K-slice.
// wb: f32 path stores cvt'd bf16 A to Abf. rdabf: read A from Abf (bf16).
__global__ __launch_bounds__(256) void gemm_frag(
    const ushort_t* __restrict__ Au, const float* __restrict__ Af,
    ushort_t* __restrict__ Abf, const ushort_t* __restrict__ Bt,
    float* __restrict__ P, const int* __restrict__ flag, int wb, int rdabf) {
  const int t = threadIdx.x;
  const int w = t >> 6, lane = t & 63;
  const int mblk = blockIdx.x >> 3;            // 128 m-blocks of 64 rows
  const int split = blockIdx.x & 7;            // XCD-local Bt k-slice
  const int l15 = lane & 15, lq = lane >> 4;
  const int kb = split * KSPAN;
  const size_t row = (size_t)mblk * 64 + w * 16 + l15;
  const size_t offA = row * NN + kb + lq * 8;          // element offset
  const ushort_t* bp = Bt + (size_t)l15 * NN + kb + lq * 8;

  const f32x4 zero = {0.f, 0.f, 0.f, 0.f};
  f32x4 acc[8];
  #pragma unroll
  for (int nt = 0; nt < 8; ++nt) acc[nt] = zero;

  const int fl = *flag;

  if (fl && !rdabf) {
    // f32-storage A: load 32B/lane, cvt to bf16 frag, optional Abf writeback.
    const float* ap = Af + offA;
    ushort_t* wp = Abf + offA;
    if (wb) {
      #pragma unroll 2
      for (int it = 0; it < KSTEPS; ++it) {
        float4 x0 = *(const float4*)ap;
        float4 x1 = *(const float4*)(ap + 4);
        short8 a = cvt8(x0, x1);
        *(short8*)wp = a;                      // bf16-A cache (exactly-once)
        #pragma unroll
        for (int nt = 0; nt < 8; ++nt) {
          short8 b = *(const short8*)(bp + (size_t)(nt * 16) * NN);
          acc[nt] = __builtin_amdgcn_mfma_f32_16x16x32_bf16(a, b, acc[nt], 0, 0, 0);
        }
        ap += 32; wp += 32; bp += 32;
      }
    } else {
      #pragma unroll 2
      for (int it = 0; it < KSTEPS; ++it) {
        float4 x0 = *(const float4*)ap;
        float4 x1 = *(const float4*)(ap + 4);
        short8 a = cvt8(x0, x1);
        #pragma unroll
        for (int nt = 0; nt < 8; ++nt) {
          short8 b = *(const short8*)(bp + (size_t)(nt * 16) * NN);
          acc[nt] = __builtin_amdgcn_mfma_f32_16x16x32_bf16(a, b, acc[nt], 0, 0, 0);
        }
        ap += 32; bp += 32;
      }
    }
  } else {
    // bf16 A: either native bf16 input, or the Abf cache written by layer 1.
    const ushort_t* Ab = (rdabf && fl) ? (const ushort_t*)Abf : Au;
    const ushort_t* ap = Ab + offA;
    #pragma unroll 2
    for (int it = 0; it < KSTEPS; ++it) {
      short8 a = *(const short8*)ap;
      #pragma unroll
      for (int nt = 0; nt < 8; ++nt) {
        short8 b = *(const short8*)(bp + (size_t)(nt * 16) * NN);
        acc[nt] = __builtin_amdgcn_mfma_f32_16x16x32_bf16(a, b, acc[nt], 0, 0, 0);
      }
      ap += 32; bp += 32;
    }
  }

  // C/D: row = lq*4 + reg (within strip), col = nt*16 + l15. Split-K atomics.
  const size_t m0 = (size_t)mblk * 64 + w * 16 + lq * 4;
  #pragma unroll
  for (int nt = 0; nt < 8; ++nt) {
    #pragma unroll
    for (int reg = 0; reg < 4; ++reg) {
      unsafeAtomicAdd(&P[(m0 + reg) * NO + nt * 16 + l15], acc[nt][reg]);
    }
  }
}

// P -> bf16, relu cols<64, TRANSPOSED (Bt layout) into ws for GEMM2.
__global__ void epi_t(const float* __restrict__ P, ushort_t* __restrict__ Ct) {
  __shared__ ushort_t lt[128 * 65];
  const size_t base = (size_t)blockIdx.x * (64 * NO);
  const int t = threadIdx.x;
  for (int i = 0; i < 32; ++i) {
    int e = i * 256 + t;
    int n = e & 127, m = e >> 7;
    float v = P[base + e];
    if (n < 64) v = fmaxf(v, 0.f);
    lt[n * 65 + m] = (ushort_t)bf16bits(v);
  }
  __syncthreads();
  const int n = t >> 1, h = t & 1;
  const size_t m0 = (size_t)blockIdx.x * 64;
  ushort_t* dst = Ct + (size_t)n * NN + m0 + h * 32;
  #pragma unroll
  for (int jj = 0; jj < 4; ++jj) {       // vectorized global stores
    short8 v;
    #pragma unroll
    for (int j = 0; j < 8; ++j) v[j] = (short)lt[n * 65 + h * 32 + jj * 8 + j];
    *(short8*)(dst + jj * 8) = v;
  }
}

// P -> relu cols<64 -> output in detected dtype.
__global__ void epi_out(const float* __restrict__ P, ushort_t* __restrict__ outb,
                        float* __restrict__ outf, const int* __restrict__ flag) {
  int idx = blockIdx.x * 256 + threadIdx.x;  // 262144 threads
  size_t e = (size_t)idx * 4;
  float4 v = *(const float4*)(P + e);
  float s[4] = {v.x, v.y, v.z, v.w};
  int n0 = (int)(e & 127);
  #pragma unroll
  for (int j = 0; j < 4; ++j) if (n0 + j < 64) s[j] = fmaxf(s[j], 0.f);
  if (*flag) {
    *(float4*)(outf + e) = make_float4(s[0], s[1], s[2], s[3]);
  } else {
    us4 r;
    #pragma unroll
    for (int j = 0; j < 4; ++j) r[j] = (ushort_t)bf16bits(s[j]);
    *(us4*)(outb + e) = r;
  }
}

extern "C" void kernel_launch(void* const* d_in, const int* in_sizes, int n_in,
                              void* d_out, int out_size, void* d_ws, size_t ws_size,
                              hipStream_t stream) {
  const ushort_t* A  = (const ushort_t*)d_in[0];   // [8192][8192]
  const ushort_t* F  = (const ushort_t*)d_in[1];   // [8192][64]
  const ushort_t* NF = (const ushort_t*)d_in[2];   // [8192][64]

  char* ws = (char*)d_ws;
  ushort_t* Bt = (ushort_t*)(ws);                  // 2 MB  [128][8192] bf16
  ushort_t* Ct = (ushort_t*)(ws + (2u << 20));     // 2 MB  [128][8192] bf16
  float*    P1 = (float*)(ws + (4u << 20));        // 4 MB  f32 [8192][128]
  float*    P2 = (float*)(ws + (8u << 20));        // 4 MB
  int*    flag = (int*)(ws + (12u << 20));         // 4 B
  ushort_t* Abf = (ushort_t*)(ws + (16u << 20));   // 128 MB [8192][8192] bf16

  const int wsok = (ws_size >= ((size_t)144 << 20)) ? 1 : 0;

  detect_dtype<<<1, 256, 0, stream>>>(A, flag);
  zero_ws<<<2048, 256, 0, stream>>>(P1);           // zeros P1+P2 (8 MB, contiguous)
  pack_bt<<<512, 256, 0, stream>>>(F, NF, Bt, flag);
  // layer 1: f32 path (if f32 storage) + Abf writeback when ws allows
  gemm_frag<<<1024, 256, 0, stream>>>(A, (const float*)A, Abf, Bt, P1, flag,
                                      wsok, 0);
  epi_t<<<128, 256, 0, stream>>>(P1, Ct);
  // layer 2: bf16 path reading Abf (half bytes, L3-warm) when available
  gemm_frag<<<1024, 256, 0, stream>>>(A, (const float*)A, Abf, Ct, P2, flag,
                                      0, wsok);
  epi_out<<<1024, 256, 0, stream>>>(P2, (ushort_t*)d_out, (float*)d_out, flag);
}

// Round 5
// 514.158 us; speedup vs baseline: 1.2748x; 1.2748x over previous
//
#include <hip/hip_runtime.h>
#include <hip/hip_bf16.h>

// out = [relu(A@relu(A@F)) | A@(A@nf)], N=8192, D=E=64.
// Two skinny GEMMs (M=8192, N=128, K=8192), relu on cols<64 after each.
// Round 8: SEQUENTIAL-STREAM layouts. Round-4 counters (MfmaUtil 2.8%,
// VALU 2.8%, HBM 16%, occ 42%) showed all pipes idle: the invariant across
// ALL prior versions was fragment-layout global addressing (consecutive
// lanes -> consecutive 32KB-strided rows => scattered half-used 64B lines,
// ~1.3TB/s effective HBM). Fix: every global access contiguous.
//  - pack_b: B in fragment-major PACKED layout (1KB contig per fragment).
//  - gemm staged: A read row-major coalesced; fragment scatter via LDS;
//    bf16 A written back PACKED (Apk, coalesced) for layer 2.
//  - epi_pack: layer-1 out -> packed fragment-major B2.
//  - gemm packed: layer 2 reads Apk/B2 fragment-direct, all loads 1KB
//    contiguous, no LDS, no barriers.
// Dtype self-detection (bf16 OR f32 storage) retained; kernels branch
// uniformly on a device flag; packed path gated on ws_size.

typedef unsigned short ushort_t;
typedef __attribute__((ext_vector_type(8))) short short8;   // 8 bf16
typedef __attribute__((ext_vector_type(4))) float f32x4;    // MFMA acc
typedef __attribute__((ext_vector_type(4))) unsigned short us4;

#define NN 8192
#define NO 128
#define NSPLIT 8
#define KSPAN 1024               // K per split
#define KSTEPS 32                // 32-k MFMA steps per span

__global__ void detect_dtype(const ushort_t* __restrict__ A, int* __restrict__ flag) {
  __shared__ int smax, szero;
  const int t = threadIdx.x;
  if (t == 0) { smax = 0; szero = 0; }
  __syncthreads();
  int lmax = 0, lzero = 0;
  #pragma unroll
  for (int j = 0; j < 8; ++j) {
    int idx = t * 8 + j;
    int u = (int)A[idx];
    if ((idx & 1) == 0) {                // little-endian: even = f32 low mantissa
      lmax = max(lmax, u);
      lzero += (u == 0) ? 1 : 0;
    }
  }
  atomicMax(&smax, lmax);
  atomicAdd(&szero, lzero);
  __syncthreads();
  if (t == 0) *flag = (smax > 0x3A00 || szero > 800) ? 1 : 0;
}

__global__ void zero_ws(float* __restrict__ p) {
  size_t i = ((size_t)blockIdx.x * 256 + threadIdx.x) * 4;
  *(float4*)(p + i) = make_float4(0.f, 0.f, 0.f, 0.f);
}

__device__ __forceinline__ short bf16bits(float x) {
  __hip_bfloat16 h = __float2bfloat16(x);
  return *reinterpret_cast<short*>(&h);
}

__device__ __forceinline__ short8 cvt8(float4 a, float4 b) {
  short8 r;
  r[0] = bf16bits(a.x); r[1] = bf16bits(a.y); r[2] = bf16bits(a.z); r[3] = bf16bits(a.w);
  r[4] = bf16bits(b.x); r[5] = bf16bits(b.y); r[6] = bf16bits(b.z); r[7] = bf16bits(b.w);
  return r;
}

// Packed fragment-major B from F|NF. Fragment (nt,ks): lane l, elem j holds
// B[k=ks*32+(l>>4)*8+j][n=nt*16+(l&15)]. 8 nt x 256 ks x 1KB = 2MB.
__global__ void pack_b(const ushort_t* __restrict__ F, const ushort_t* __restrict__ NF,
                       ushort_t* __restrict__ Bpk, const int* __restrict__ flag) {
  int gid = blockIdx.x * 256 + threadIdx.x;   // 131072 = 8*256*64
  int l = gid & 63, ks = (gid >> 6) & 255, nt = gid >> 14;
  int n = nt * 16 + (l & 15);
  int k0 = ks * 32 + (l >> 4) * 8;
  ushort_t* dst = Bpk + (((size_t)nt * 256 + ks) << 9) + l * 8;
  short8 v;
  if (*flag) {
    const float* src = (n < 64) ? ((const float*)F + n) : ((const float*)NF + n - 64);
    #pragma unroll
    for (int j = 0; j < 8; ++j) v[j] = bf16bits(src[(size_t)(k0 + j) << 6]);
  } else {
    const ushort_t* src = (n < 64) ? (F + n) : (NF + n - 64);
    #pragma unroll
    for (int j = 0; j < 8; ++j) v[j] = (short)src[(size_t)(k0 + j) << 6];
  }
  *(short8*)dst = v;
}

// mfma_f32_16x16x32_bf16 (verified): A-frag lane l -> A[m=l&15][k=(l>>4)*8+j];
// B-frag lane l -> B[k=(l>>4)*8+j][n=l&15]; C/D: col=l&15, row=(l>>4)*4+reg.
//
// Unified GEMM: P[m0:m0+64][0:128] += A[m0:m0+64][kb:kb+1024] @ B (atomics).
//  - usepk && fl: fragment-direct from packed Apk (contig 1KB loads, no LDS).
//  - else staged: A read ROW-MAJOR COALESCED (4 thr/row), LDS scatter to
//    fragment order, per-wave seg read. wb && fl: write packed Apk.
__global__ __launch_bounds__(256) void gemm(
    const ushort_t* __restrict__ Au, const float* __restrict__ Af,
    ushort_t* __restrict__ Apk, const ushort_t* __restrict__ Bpk,
    float* __restrict__ P, const int* __restrict__ flag, int wb, int usepk) {
  __shared__ __align__(16) ushort_t lsA[4 * 512];   // 4KB: 4 segs of 16 rows
  const int t = threadIdx.x;
  const int w = t >> 6, lane = t & 63;
  const int mblk = blockIdx.x >> 3;                 // 128 m-blocks of 64 rows
  const int split = blockIdx.x & 7;
  const size_t m0 = (size_t)mblk * 64;
  const int ks0 = split * KSTEPS;                   // global 32-k step base
  const int l15 = lane & 15, lq = lane >> 4;
  const int fl = *flag;

  const f32x4 zero = {0.f, 0.f, 0.f, 0.f};
  f32x4 acc[8];
  #pragma unroll
  for (int nt = 0; nt < 8; ++nt) acc[nt] = zero;

  if (usepk && fl) {
    // ---- fragment-direct: all loads contiguous 1KB per wave-instr ----
    const ushort_t* ap = Apk + (((size_t)(mblk * 4 + w) * 256 + ks0) << 9) + lane * 8;
    const ushort_t* bp = Bpk + ((size_t)ks0 << 9) + lane * 8;
    #pragma unroll 2
    for (int it = 0; it < KSTEPS; ++it) {
      short8 a = *(const short8*)ap;
      #pragma unroll
      for (int nt = 0; nt < 8; ++nt) {
        short8 b = *(const short8*)(bp + ((size_t)nt << 17));
        acc[nt] = __builtin_amdgcn_mfma_f32_16x16x32_bf16(a, b, acc[nt], 0, 0, 0);
      }
      ap += 512; bp += 512;
    }
  } else {
    // ---- staged: coalesced row-major A -> LDS fragment scatter ----
    const int r = t >> 2, cq = t & 3;               // row 0..63, 8-elem chunk
    const int mt = r >> 4;                          // LDS seg (16-row group)
    const int li = (r & 15) + cq * 16;              // lane slot in fragment
    const float*    ap_f = Af + (m0 + r) * NN + (size_t)ks0 * 32 + cq * 8;
    const ushort_t* ap_b = Au + (m0 + r) * NN + (size_t)ks0 * 32 + cq * 8;
    ushort_t* wp = Apk + (((size_t)(mblk * 4 + mt) * 256 + ks0) << 9) + li * 8;
    ushort_t* lw = lsA + mt * 512 + li * 8;
    const ushort_t* lr = lsA + w * 512 + lane * 8;
    const int dowb = wb && fl;
    for (int it = 0; it < KSTEPS; ++it) {
      short8 c;
      if (fl) {
        float4 x0 = *(const float4*)ap_f;
        float4 x1 = *(const float4*)(ap_f + 4);
        c = cvt8(x0, x1);
        ap_f += 32;
      } else {
        c = *(const short8*)ap_b;
        ap_b += 32;
      }
      if (dowb) { *(short8*)wp = c; wp += 512; }    // packed A for layer 2
      const ushort_t* bit = Bpk + ((size_t)(ks0 + it) << 9) + lane * 8;
      __syncthreads();                               // prior readers done
      *(short8*)lw = c;
      __syncthreads();
      short8 a = *(const short8*)lr;                 // wave w: rows w*16..+15
      #pragma unroll
      for (int nt = 0; nt < 8; ++nt) {
        short8 b = *(const short8*)(bit + ((size_t)nt << 17));
        acc[nt] = __builtin_amdgcn_mfma_f32_16x16x32_bf16(a, b, acc[nt], 0, 0, 0);
      }
    }
  }

  // C/D: row = w*16 + lq*4 + reg, col = nt*16 + l15. Split-K atomics.
  const size_t mrow = m0 + w * 16 + lq * 4;
  #pragma unroll
  for (int nt = 0; nt < 8; ++nt) {
    #pragma unroll
    for (int reg = 0; reg < 4; ++reg) {
      unsafeAtomicAdd(&P[(mrow + reg) * NO + nt * 16 + l15], acc[nt][reg]);
    }
  }
}

// Layer-1 epilogue: P1 -> relu cols<64 -> bf16 packed fragment-major B2.
// Block b covers k-rows [b*64, b*64+64) = ks {2b, 2b+1}.
__global__ void epi_pack(const float* __restrict__ P, ushort_t* __restrict__ Bpk2) {
  __shared__ ushort_t lt[64 * 130];
  const int t = threadIdx.x;
  const int blk = blockIdx.x;
  const size_t base = (size_t)blk * 64 * NO;
  #pragma unroll
  for (int i = 0; i < 8; ++i) {
    int e4 = (i * 256 + t) * 4;
    int m = e4 >> 7, n = e4 & 127;
    float4 v = *(const float4*)(P + base + e4);
    float s[4] = {v.x, v.y, v.z, v.w};
    if (n < 64) {                                    // n is 4-aligned: all-or-none
      #pragma unroll
      for (int j = 0; j < 4; ++j) s[j] = fmaxf(s[j], 0.f);
    }
    #pragma unroll
    for (int j = 0; j < 4; ++j) lt[m * 130 + n + j] = (ushort_t)bf16bits(s[j]);
  }
  __syncthreads();
  #pragma unroll
  for (int i = 0; i < 4; ++i) {
    int item = i * 256 + t;                          // 1024 fragments-of-16B
    int l = item & 63, s = (item >> 6) & 1, nt = item >> 7;
    short8 v;
    #pragma unroll
    for (int j = 0; j < 8; ++j)
      v[j] = (short)lt[(s * 32 + (l >> 4) * 8 + j) * 130 + nt * 16 + (l & 15)];
    *(short8*)(Bpk2 + (((size_t)nt * 256 + blk * 2 + s) << 9) + l * 8) = v;
  }
}

// P2 -> relu cols<64 -> output in detected dtype.
__global__ void epi_out(const float* __restrict__ P, ushort_t* __restrict__ outb,
                        float* __restrict__ outf, const int* __restrict__ flag) {
  int idx = blockIdx.x * 256 + threadIdx.x;
  size_t e = (size_t)idx * 4;
  float4 v = *(const float4*)(P + e);
  float s[4] = {v.x, v.y, v.z, v.w};
  int n0 = (int)(e & 127);
  #pragma unroll
  for (int j = 0; j < 4; ++j) if (n0 + j < 64) s[j] = fmaxf(s[j], 0.f);
  if (*flag) {
    *(float4*)(outf + e) = make_float4(s[0], s[1], s[2], s[3]);
  } else {
    us4 r;
    #pragma unroll
    for (int j = 0; j < 4; ++j) r[j] = (ushort_t)bf16bits(s[j]);
    *(us4*)(outb + e) = r;
  }
}

extern "C" void kernel_launch(void* const* d_in, const int* in_sizes, int n_in,
                              void* d_out, int out_size, void* d_ws, size_t ws_size,
                              hipStream_t stream) {
  const ushort_t* A  = (const ushort_t*)d_in[0];   // [8192][8192]
  const ushort_t* F  = (const ushort_t*)d_in[1];   // [8192][64]
  const ushort_t* NF = (const ushort_t*)d_in[2];   // [8192][64]

  char* ws = (char*)d_ws;
  ushort_t* Bpk1 = (ushort_t*)(ws);                // 2 MB packed B (layer 1)
  ushort_t* Bpk2 = (ushort_t*)(ws + (2u << 20));   // 2 MB packed B (layer 2)
  float*    P1   = (float*)(ws + (4u << 20));      // 4 MB f32 [8192][128]
  float*    P2   = (float*)(ws + (8u << 20));      // 4 MB
  int*      flag = (int*)(ws + (12u << 20));       // 4 B
  ushort_t* Apk  = (ushort_t*)(ws + (16u << 20));  // 128 MB packed bf16 A

  const int wsok = (ws_size >= ((size_t)144 << 20) + 4) ? 1 : 0;

  detect_dtype<<<1, 256, 0, stream>>>(A, flag);
  zero_ws<<<2048, 256, 0, stream>>>(P1);           // zeros P1+P2 (8 MB contig)
  pack_b<<<512, 256, 0, stream>>>(F, NF, Bpk1, flag);
  // layer 1: staged (coalesced A) + packed-A writeback when ws allows
  gemm<<<1024, 256, 0, stream>>>(A, (const float*)A, Apk, Bpk1, P1, flag,
                                 wsok, 0);
  epi_pack<<<128, 256, 0, stream>>>(P1, Bpk2);
  // layer 2: fragment-direct from Apk when (flag&&wsok), else staged from A
  gemm<<<1024, 256, 0, stream>>>(A, (const float*)A, Apk, Bpk2, P2, flag,
                                 0, wsok);
  epi_out<<<1024, 256, 0, stream>>>(P2, (ushort_t*)d_out, (float*)d_out, flag);
}

// Round 6
// 505.495 us; speedup vs baseline: 1.2966x; 1.0171x over previous
//
#include <hip/hip_runtime.h>
#include <hip/hip_bf16.h>

// out = [relu(A@relu(A@F)) | A@(A@nf)], N=8192, D=E=64.
// Round 9: long-burst streaming, atomic-free GEMM.
// R5 counters: BW 1.8TB/s (29% ach.), MfmaUtil 3.9%, occ 41% -> DRAM page
// thrash: 65k row-streams touched 128B each. Fix:
//  - block = 16 rows x N=128; 4 waves split K privately (2048 each), NO
//    main-loop barriers; stage 2KB-contig-per-row bursts into wave-private
//    swizzled LDS; frag-read + MFMA; one barrier; cross-wave LDS reduce;
//    plain coalesced stores. No split-K atomics, no zero pass.
//  - GEMM1 fuses B2 fragment-pack epilogue (P1 gone); writes packed bf16 A
//    (Apk) for layer 2. GEMM2 reads Apk fragment-direct (1KB contig streams,
//    no LDS for A) and fuses relu+final store (P2/epi_out gone).
//  - 4 dispatches total. Dtype self-detection (bf16/f32 storage) retained.

typedef unsigned short ushort_t;
typedef __attribute__((ext_vector_type(8))) short short8;   // 8 bf16
typedef __attribute__((ext_vector_type(4))) float f32x4;    // MFMA acc
typedef __attribute__((ext_vector_type(4))) unsigned short us4;

#define NN 8192
#define NO 128

__global__ void detect_dtype(const ushort_t* __restrict__ A, int* __restrict__ flag) {
  __shared__ int smax, szero;
  const int t = threadIdx.x;
  if (t == 0) { smax = 0; szero = 0; }
  __syncthreads();
  int lmax = 0, lzero = 0;
  #pragma unroll
  for (int j = 0; j < 8; ++j) {
    int idx = t * 8 + j;
    int u = (int)A[idx];
    if ((idx & 1) == 0) {                // little-endian: even = f32 low mantissa
      lmax = max(lmax, u);
      lzero += (u == 0) ? 1 : 0;
    }
  }
  atomicMax(&smax, lmax);
  atomicAdd(&szero, lzero);
  __syncthreads();
  if (t == 0) *flag = (smax > 0x3A00 || szero > 800) ? 1 : 0;
}

__device__ __forceinline__ short bf16bits(float x) {
  __hip_bfloat16 h = __float2bfloat16(x);
  return *reinterpret_cast<short*>(&h);
}

// Packed fragment-major B from F|NF. Fragment (nt,ks): lane l, elem j holds
// B[k=ks*32+(l>>4)*8+j][n=nt*16+(l&15)]. 8 nt x 256 ks x 1KB = 2MB.
__global__ void pack_b(const ushort_t* __restrict__ F, const ushort_t* __restrict__ NF,
                       ushort_t* __restrict__ Bpk, const int* __restrict__ flag) {
  int gid = blockIdx.x * 256 + threadIdx.x;   // 131072 = 8*256*64
  int l = gid & 63, ks = (gid >> 6) & 255, nt = gid >> 14;
  int n = nt * 16 + (l & 15);
  int k0 = ks * 32 + (l >> 4) * 8;
  ushort_t* dst = Bpk + (((size_t)nt * 256 + ks) << 9) + l * 8;
  short8 v;
  if (*flag) {
    const float* src = (n < 64) ? ((const float*)F + n) : ((const float*)NF + n - 64);
    #pragma unroll
    for (int j = 0; j < 8; ++j) v[j] = bf16bits(src[(size_t)(k0 + j) << 6]);
  } else {
    const ushort_t* src = (n < 64) ? (F + n) : (NF + n - 64);
    #pragma unroll
    for (int j = 0; j < 8; ++j) v[j] = (short)src[(size_t)(k0 + j) << 6];
  }
  *(short8*)dst = v;
}

// mfma_f32_16x16x32_bf16 (verified): A-frag lane l -> A[m=l&15][k=(l>>4)*8+j];
// B-frag lane l -> B[k=(l>>4)*8+j][n=l&15]; C/D: col=l&15, row=(l>>4)*4+reg.
//
// Block b: rows [b*16,b*16+16), cols [0,128), full K=8192. Wave w: k-span
// [w*2048,(w+1)*2048) in 4 supersteps of 512. Stage: per row 2KB(f32)/1KB
// (bf16) contiguous burst -> wave-private LDS (16KB, XOR-swizzled). Then 16
// frag-reads + 128 MFMA per superstep. No barriers until the final reduce.
// usepk&&fl: skip staging, stream A-frags from packed Apk (contig 1KB/instr).
// wb&&fl: write frag-packed bf16 A to Apk. outmode 0: pack B2 frags (+relu
// n<64). outmode 1: final store (+relu n<64) in detected dtype.
__global__ __launch_bounds__(256) void gemm(
    const ushort_t* __restrict__ Au, const float* __restrict__ Af,
    ushort_t* __restrict__ Apk, const ushort_t* __restrict__ Bpk,
    ushort_t* __restrict__ Bpk2, ushort_t* __restrict__ outb,
    float* __restrict__ outf, const int* __restrict__ flag,
    int wb, int usepk, int outmode) {
  __shared__ __align__(16) char lds[65536];    // 4 x 16KB stage | 32KB reduce
  const int t = threadIdx.x;
  const int w = t >> 6, lane = t & 63;
  const int b = blockIdx.x;                    // [0,512)
  const int l15 = lane & 15, lq = lane >> 4;
  const int fl = *flag;

  const f32x4 zero = {0.f, 0.f, 0.f, 0.f};
  f32x4 acc[8];
  #pragma unroll
  for (int nt = 0; nt < 8; ++nt) acc[nt] = zero;

  if (usepk && fl) {
    // ---- fragment-direct: wave streams 64KB of Apk contiguously ----
    const ushort_t* ap = Apk + (((size_t)b * 256 + w * 64) << 9) + lane * 8;
    const ushort_t* bp = Bpk + (((size_t)w * 64) << 9) + lane * 8;
    #pragma unroll 2
    for (int kk = 0; kk < 64; ++kk) {
      short8 a = *(const short8*)(ap + ((size_t)kk << 9));
      #pragma unroll
      for (int nt = 0; nt < 8; ++nt) {
        short8 bfr = *(const short8*)(bp + ((size_t)nt << 17) + ((size_t)kk << 9));
        acc[nt] = __builtin_amdgcn_mfma_f32_16x16x32_bf16(a, bfr, acc[nt], 0, 0, 0);
      }
    }
  } else {
    char* myA = lds + w * 16384;               // wave-private 16KB
    const size_t row0 = (size_t)b * 16;
    const int dowb = wb && fl;
    for (int s = 0; s < 4; ++s) {
      const int k0 = w * 2048 + s * 512;       // element offset within row
      // ---- stage 16 rows x 512 elems, long contiguous bursts per row ----
      if (fl) {
        #pragma unroll 4
        for (int r = 0; r < 16; ++r) {
          const float* src = Af + (row0 + r) * NN + k0 + lane * 4;
          float4 x0 = *(const float4*)src;
          float4 x1 = *(const float4*)(src + 256);
          const int swz = (r & 7) << 4;
          us4 v0, v1;
          v0[0] = (ushort_t)bf16bits(x0.x); v0[1] = (ushort_t)bf16bits(x0.y);
          v0[2] = (ushort_t)bf16bits(x0.z); v0[3] = (ushort_t)bf16bits(x0.w);
          v1[0] = (ushort_t)bf16bits(x1.x); v1[1] = (ushort_t)bf16bits(x1.y);
          v1[2] = (ushort_t)bf16bits(x1.z); v1[3] = (ushort_t)bf16bits(x1.w);
          *(us4*)(myA + r * 1024 + ((lane * 8) ^ swz)) = v0;
          *(us4*)(myA + r * 1024 + ((512 + lane * 8) ^ swz)) = v1;
        }
      } else {
        #pragma unroll 4
        for (int r = 0; r < 16; ++r) {
          short8 x = *(const short8*)(Au + (row0 + r) * NN + k0 + lane * 8);
          const int swz = (r & 7) << 4;
          *(short8*)(myA + r * 1024 + ((lane * 16) ^ swz)) = x;
        }
      }
      // ---- 16 MFMA steps from own LDS (no barrier: wave-private) ----
      #pragma unroll 2
      for (int kk = 0; kk < 16; ++kk) {
        short8 a = *(const short8*)(myA + l15 * 1024 +
                                    (((kk * 64) + lq * 16) ^ ((l15 & 7) << 4)));
        const int ks = w * 64 + s * 16 + kk;
        if (dowb)
          *(short8*)(Apk + (((size_t)b * 256 + ks) << 9) + lane * 8) = a;
        const ushort_t* bp = Bpk + ((size_t)ks << 9) + lane * 8;
        #pragma unroll
        for (int nt = 0; nt < 8; ++nt) {
          short8 bfr = *(const short8*)(bp + ((size_t)nt << 17));
          acc[nt] = __builtin_amdgcn_mfma_f32_16x16x32_bf16(a, bfr, acc[nt], 0, 0, 0);
        }
      }
    }
  }

  // ---- cross-wave reduce: LDS f32 [4][16][128] ----
  __syncthreads();
  float* red = (float*)lds;
  #pragma unroll
  for (int nt = 0; nt < 8; ++nt) {
    #pragma unroll
    for (int reg = 0; reg < 4; ++reg)
      red[w * 2048 + (lq * 4 + reg) * 128 + nt * 16 + l15] = acc[nt][reg];
  }
  __syncthreads();
  const int i = t * 8;                          // flat [m][n], m=t>>4, n0=(t&15)*8
  const int m = t >> 4, n0 = (t & 15) * 8;
  float s8[8];
  #pragma unroll
  for (int j = 0; j < 8; ++j)
    s8[j] = red[i + j] + red[2048 + i + j] + red[4096 + i + j] + red[6144 + i + j];
  if (n0 < 64) {                                // n0 8-aligned: all-or-none
    #pragma unroll
    for (int j = 0; j < 8; ++j) s8[j] = fmaxf(s8[j], 0.f);
  }

  if (outmode == 0) {
    // pack B2 fragments: value = layer1[b*16+m][n] -> frag(nt=n>>4, ks=b>>1),
    // lane=(n&15)+((m>>3)+2*(b&1))*16, elem j=m&7.
    const int ks = b >> 1, hs = b & 1;
    #pragma unroll
    for (int j = 0; j < 8; ++j) {
      const int n = n0 + j;
      const int nt = n >> 4;
      const int ld = (n & 15) + ((m >> 3) + 2 * hs) * 16;
      Bpk2[(((size_t)nt * 256 + ks) << 9) + ld * 8 + (m & 7)] =
          (ushort_t)bf16bits(s8[j]);
    }
  } else {
    const size_t e = (size_t)b * 2048 + i;      // row-major [8192][128]
    if (fl) {
      *(float4*)(outf + e)     = make_float4(s8[0], s8[1], s8[2], s8[3]);
      *(float4*)(outf + e + 4) = make_float4(s8[4], s8[5], s8[6], s8[7]);
    } else {
      short8 r;
      #pragma unroll
      for (int j = 0; j < 8; ++j) r[j] = bf16bits(s8[j]);
      *(short8*)(outb + e) = r;
    }
  }
}

extern "C" void kernel_launch(void* const* d_in, const int* in_sizes, int n_in,
                              void* d_out, int out_size, void* d_ws, size_t ws_size,
                              hipStream_t stream) {
  const ushort_t* A  = (const ushort_t*)d_in[0];   // [8192][8192]
  const ushort_t* F  = (const ushort_t*)d_in[1];   // [8192][64]
  const ushort_t* NF = (const ushort_t*)d_in[2];   // [8192][64]

  char* ws = (char*)d_ws;
  ushort_t* Bpk1 = (ushort_t*)(ws);                // 2 MB packed B (layer 1)
  ushort_t* Bpk2 = (ushort_t*)(ws + (2u << 20));   // 2 MB packed B (layer 2)
  int*      flag = (int*)(ws + (4u << 20));        // 4 B
  ushort_t* Apk  = (ushort_t*)(ws + (8u << 20));   // 128 MB frag-packed bf16 A

  const int wsok = (ws_size >= ((size_t)144 << 20)) ? 1 : 0;

  detect_dtype<<<1, 256, 0, stream>>>(A, flag);
  pack_b<<<512, 256, 0, stream>>>(F, NF, Bpk1, flag);
  // layer 1: staged long-burst A; writes packed Apk (ws-gated) + packed B2
  gemm<<<512, 256, 0, stream>>>(A, (const float*)A, Apk, Bpk1, Bpk2,
                                nullptr, nullptr, flag, wsok, 0, 0);
  // layer 2: fragment-direct from Apk when (flag&&wsok), else staged from A;
  // fused relu + final store in detected dtype
  gemm<<<512, 256, 0, stream>>>(A, (const float*)A, Apk, Bpk2, Bpk2,
                                (ushort_t*)d_out, (float*)d_out, flag,
                                0, wsok, 1);
}